// Round 1
// baseline (126.099 us; speedup 1.0000x reference)
//
#include <hip/hip_runtime.h>
#include <stdint.h>

// Problem constants (from reference setup_inputs)
#define BATCH 4096
#define ISZ   512
#define OSZ   512
#define ORD8  8
#define KDIM  (ISZ * ORD8)   // 4096, contraction dim: k = i*8 + d

typedef __bf16 bf16x8 __attribute__((ext_vector_type(8)));
typedef float  f32x4  __attribute__((ext_vector_type(4)));

__device__ __forceinline__ unsigned short f2bf(float f) {
    // round-to-nearest-even fp32 -> bf16 (no NaN inputs here)
    uint32_t u = __float_as_uint(f);
    u = (u + 0x7FFFu + ((u >> 16) & 1u)) >> 16;
    return (unsigned short)u;
}

// jac[b][i*8+d] = P_d(tanh(x[b][i])), alpha=beta=1 Jacobi recurrence.
// K2[i]=0 (a==b); K1/K3 precomputed on host side of the math:
//   K1 = {1.875, 1.8666667, 1.875, 1.8857143, 1.8958333, 1.9047619}
//   K3 = (i+1)/(i+2)
__global__ __launch_bounds__(256) void jacobi_precompute(
    const float* __restrict__ x, unsigned short* __restrict__ jac, int n)
{
    int idx = blockIdx.x * 256 + threadIdx.x;
    if (idx >= n) return;
    float t  = tanhf(x[idx]);
    float p0 = 1.0f;
    float p1 = 2.0f * t;                       // 0.5*(a+b+2)*x - 0.5*(a-b)
    float p2 = (1.875f     * t) * p1 - 0.75f       * p0;
    float p3 = (1.8666667f * t) * p2 - 0.8f        * p1;
    float p4 = (1.875f     * t) * p3 - 0.83333333f * p2;
    float p5 = (1.8857143f * t) * p4 - 0.85714287f * p3;
    float p6 = (1.8958333f * t) * p5 - 0.875f      * p4;
    float p7 = (1.9047619f * t) * p6 - 0.88888889f * p5;
    uint4 o;
    o.x = (uint32_t)f2bf(p0) | ((uint32_t)f2bf(p1) << 16);
    o.y = (uint32_t)f2bf(p2) | ((uint32_t)f2bf(p3) << 16);
    o.z = (uint32_t)f2bf(p4) | ((uint32_t)f2bf(p5) << 16);
    o.w = (uint32_t)f2bf(p6) | ((uint32_t)f2bf(p7) << 16);
    *reinterpret_cast<uint4*>(jac + (size_t)idx * 8) = o;   // 16B aligned
}

// flat fp32 -> bf16 convert (coef is already k-contiguous: [O][I][D] -> [O][K])
__global__ __launch_bounds__(256) void convert_bf16(
    const float* __restrict__ src, unsigned short* __restrict__ dst, int n4)
{
    int idx = blockIdx.x * 256 + threadIdx.x;
    if (idx >= n4) return;
    float4 v = reinterpret_cast<const float4*>(src)[idx];
    uint2 o;
    o.x = (uint32_t)f2bf(v.x) | ((uint32_t)f2bf(v.y) << 16);
    o.y = (uint32_t)f2bf(v.z) | ((uint32_t)f2bf(v.w) << 16);
    reinterpret_cast<uint2*>(dst)[idx] = o;
}

// C[M][N] = A[M][K] * Bm[N][K]^T, bf16 inputs, fp32 out.
// 64x64 tile, BK=64, 256 threads = 4 waves (2x2), each wave 32x32 via
// 2x2 of mfma_f32_16x16x32_bf16. Staging via global_load_lds width=16
// (wave-uniform LDS base + lane*16 contiguous chunk mapping, unpadded).
__global__ __launch_bounds__(256) void gemm_bt64(
    const unsigned short* __restrict__ A,   // [M][K] bf16 bits
    const unsigned short* __restrict__ Bm,  // [N][K] bf16 bits
    float* __restrict__ C, int M, int N, int K)
{
    __shared__ __align__(16) unsigned short As[64 * 64];
    __shared__ __align__(16) unsigned short Bs[64 * 64];

    const int tid  = threadIdx.x;
    const int wave = tid >> 6;
    const int lane = tid & 63;
    const int wm   = (wave >> 1) * 32;      // wave row offset in tile
    const int wn   = (wave & 1) * 32;       // wave col offset in tile

    const size_t baseA = (size_t)blockIdx.x * 64 * K;
    const size_t baseB = (size_t)blockIdx.y * 64 * K;

    f32x4 acc[2][2] = {};

    const int mrow = lane & 15;             // m within 16x16 tile
    const int krow = (lane >> 4) * 8;       // k sub-block within 32

    for (int k0 = 0; k0 < K; k0 += 64) {
        // stage A and B tiles: 64x64 bf16 each = 8 KB; 512 chunks of 16B,
        // 256 threads x 2 iterations. chunk c -> LDS bytes [c*16, c*16+16),
        // global row = c/8, col = (c%8)*8.
        #pragma unroll
        for (int it = 0; it < 2; ++it) {
            int c   = it * 256 + tid;
            int row = c >> 3;
            int col = (c & 7) * 8;
            const unsigned short* gA = A  + baseA + (size_t)row * K + k0 + col;
            const unsigned short* gB = Bm + baseB + (size_t)row * K + k0 + col;
            unsigned short* lA = As + (it * 256 + wave * 64) * 8; // wave-uniform
            unsigned short* lB = Bs + (it * 256 + wave * 64) * 8;
            __builtin_amdgcn_global_load_lds(
                (const __attribute__((address_space(1))) uint32_t*)gA,
                (__attribute__((address_space(3))) uint32_t*)lA, 16, 0, 0);
            __builtin_amdgcn_global_load_lds(
                (const __attribute__((address_space(1))) uint32_t*)gB,
                (__attribute__((address_space(3))) uint32_t*)lB, 16, 0, 0);
        }
        __syncthreads();   // waits vmcnt(0) for global_load_lds

        #pragma unroll
        for (int ks = 0; ks < 64; ks += 32) {
            bf16x8 aF[2], bF[2];
            #pragma unroll
            for (int mi = 0; mi < 2; ++mi)
                aF[mi] = *reinterpret_cast<const bf16x8*>(
                    As + (wm + mi * 16 + mrow) * 64 + ks + krow);
            #pragma unroll
            for (int ni = 0; ni < 2; ++ni)
                bF[ni] = *reinterpret_cast<const bf16x8*>(
                    Bs + (wn + ni * 16 + mrow) * 64 + ks + krow);
            #pragma unroll
            for (int mi = 0; mi < 2; ++mi)
                #pragma unroll
                for (int ni = 0; ni < 2; ++ni)
                    acc[mi][ni] = __builtin_amdgcn_mfma_f32_16x16x32_bf16(
                        aF[mi], bF[ni], acc[mi][ni], 0, 0, 0);
        }
        __syncthreads();
    }

    // C/D layout (m89-verified): col = lane&15, row = (lane>>4)*4 + r
    const int orow = blockIdx.x * 64 + wm + (lane >> 4) * 4;
    const int ocol = blockIdx.y * 64 + wn + (lane & 15);
    #pragma unroll
    for (int mi = 0; mi < 2; ++mi)
        #pragma unroll
        for (int ni = 0; ni < 2; ++ni)
            #pragma unroll
            for (int r = 0; r < 4; ++r)
                C[(size_t)(orow + mi * 16 + r) * N + ocol + ni * 16] =
                    acc[mi][ni][r];
}

extern "C" void kernel_launch(void* const* d_in, const int* in_sizes, int n_in,
                              void* d_out, int out_size, void* d_ws, size_t ws_size,
                              hipStream_t stream)
{
    const float* x    = (const float*)d_in[0];   // [4096][512]
    const float* coef = (const float*)d_in[1];   // [512][512][8]
    float* out = (float*)d_out;                  // [4096][512]

    // workspace: jac bf16 [4096][4096] (32 MB) + coef bf16 [512][4096] (4 MB)
    unsigned short* jac   = (unsigned short*)d_ws;
    unsigned short* coefb = jac + (size_t)BATCH * KDIM;

    int nx = BATCH * ISZ;                        // 2,097,152
    jacobi_precompute<<<(nx + 255) / 256, 256, 0, stream>>>(x, jac, nx);

    int n4 = (OSZ * KDIM) / 4;                   // 524,288
    convert_bf16<<<(n4 + 255) / 256, 256, 0, stream>>>(coef, coefb, n4);

    dim3 grid(BATCH / 64, OSZ / 64);             // 64 x 8 = 512 blocks
    gemm_bt64<<<grid, 256, 0, stream>>>(jac, coefb, out, BATCH, OSZ, KDIM);
}

// Round 2
// 118.852 us; speedup vs baseline: 1.0610x; 1.0610x over previous
//
#include <hip/hip_runtime.h>
#include <stdint.h>

// Problem constants (from reference setup_inputs)
#define BATCH 4096
#define ISZ   512
#define OSZ   512
#define ORD8  8
#define KDIM  (ISZ * ORD8)   // 4096, contraction dim: k = i*8 + d
#define SPLITK 4

typedef __bf16 bf16x8 __attribute__((ext_vector_type(8)));
typedef float  f32x4  __attribute__((ext_vector_type(4)));

__device__ __forceinline__ unsigned short f2bf(float f) {
    // round-to-nearest-even fp32 -> bf16 (no NaN inputs here)
    uint32_t u = __float_as_uint(f);
    u = (u + 0x7FFFu + ((u >> 16) & 1u)) >> 16;
    return (unsigned short)u;
}

// jac[b][i*8+d] = P_d(tanh(x[b][i])), alpha=beta=1 Jacobi recurrence.
__global__ __launch_bounds__(256) void jacobi_precompute(
    const float* __restrict__ x, unsigned short* __restrict__ jac, int n)
{
    int idx = blockIdx.x * 256 + threadIdx.x;
    if (idx >= n) return;
    float t  = tanhf(x[idx]);
    float p0 = 1.0f;
    float p1 = 2.0f * t;                       // 0.5*(a+b+2)*x - 0.5*(a-b)
    float p2 = (1.875f     * t) * p1 - 0.75f       * p0;
    float p3 = (1.8666667f * t) * p2 - 0.8f        * p1;
    float p4 = (1.875f     * t) * p3 - 0.83333333f * p2;
    float p5 = (1.8857143f * t) * p4 - 0.85714287f * p3;
    float p6 = (1.8958333f * t) * p5 - 0.875f      * p4;
    float p7 = (1.9047619f * t) * p6 - 0.88888889f * p5;
    uint4 o;
    o.x = (uint32_t)f2bf(p0) | ((uint32_t)f2bf(p1) << 16);
    o.y = (uint32_t)f2bf(p2) | ((uint32_t)f2bf(p3) << 16);
    o.z = (uint32_t)f2bf(p4) | ((uint32_t)f2bf(p5) << 16);
    o.w = (uint32_t)f2bf(p6) | ((uint32_t)f2bf(p7) << 16);
    *reinterpret_cast<uint4*>(jac + (size_t)idx * 8) = o;   // 16B aligned
}

// flat fp32 -> bf16 convert (coef already k-contiguous: [O][I][D] -> [O][K])
__global__ __launch_bounds__(256) void convert_bf16(
    const float* __restrict__ src, unsigned short* __restrict__ dst, int n4)
{
    int idx = blockIdx.x * 256 + threadIdx.x;
    if (idx >= n4) return;
    float4 v = reinterpret_cast<const float4*>(src)[idx];
    uint2 o;
    o.x = (uint32_t)f2bf(v.x) | ((uint32_t)f2bf(v.y) << 16);
    o.y = (uint32_t)f2bf(v.z) | ((uint32_t)f2bf(v.w) << 16);
    reinterpret_cast<uint2*>(dst)[idx] = o;
}

// C[M][N] += A[M][K_s] * Bm[N][K_s]^T over split-K partitions (atomicAdd).
// 128x128 block tile, BK=64, 256 threads = 4 waves (2x2), wave tile 64x64
// via 4x4 of mfma_f32_16x16x32_bf16. LDS tiles stored as 16B chunks with
// XOR swizzle: chunk (row, c) lives at slot row*8 + (c ^ (row&7)), making
// fragment reads 2-way-per-bank (free) while global_load_lds keeps its
// wave-uniform-base + lane*16 destination contract (swizzle applied to the
// per-lane *source* address).
__global__ __launch_bounds__(256) void gemm_splitk(
    const unsigned short* __restrict__ A,   // [M][K] bf16 bits
    const unsigned short* __restrict__ Bm,  // [N][K] bf16 bits
    float* __restrict__ C, int M, int N, int K)
{
    __shared__ __align__(16) unsigned short As[128 * 64];
    __shared__ __align__(16) unsigned short Bs[128 * 64];

    const int tid  = threadIdx.x;
    const int wave = tid >> 6;
    const int lane = tid & 63;
    const int wm   = (wave >> 1) * 64;      // wave row offset in tile
    const int wn   = (wave & 1) * 64;       // wave col offset in tile

    const size_t baseA = (size_t)blockIdx.x * 128 * K;
    const size_t baseB = (size_t)blockIdx.y * 128 * K;
    const int kper = K / SPLITK;
    const int kbeg = blockIdx.z * kper;
    const int kend = kbeg + kper;

    f32x4 acc[4][4] = {};

    const int mrow = lane & 15;             // m within 16x16 tile
    const int kc   = lane >> 4;             // 16B-chunk column offset within k

    for (int k0 = kbeg; k0 < kend; k0 += 64) {
        // stage A and B tiles: 128x64 bf16 each = 16 KB = 1024 chunks of 16B.
        // 256 threads x 4 iterations. slot s = it*256 + tid; LDS dest is
        // wave-uniform base (it*256 + wave*64)*16 + lane*16 = s*16.
        // source chunk for slot s: row = s>>3, c = (s&7) ^ (row&7).
        #pragma unroll
        for (int it = 0; it < 4; ++it) {
            int s    = it * 256 + tid;
            int row  = s >> 3;
            int csrc = (s & 7) ^ (row & 7);
            const unsigned short* gA = A  + baseA + (size_t)row * K + k0 + csrc * 8;
            const unsigned short* gB = Bm + baseB + (size_t)row * K + k0 + csrc * 8;
            unsigned short* lA = As + (size_t)(it * 256 + wave * 64) * 8; // uniform
            unsigned short* lB = Bs + (size_t)(it * 256 + wave * 64) * 8;
            __builtin_amdgcn_global_load_lds(
                (const __attribute__((address_space(1))) uint32_t*)gA,
                (__attribute__((address_space(3))) uint32_t*)lA, 16, 0, 0);
            __builtin_amdgcn_global_load_lds(
                (const __attribute__((address_space(1))) uint32_t*)gB,
                (__attribute__((address_space(3))) uint32_t*)lB, 16, 0, 0);
        }
        __syncthreads();   // drains vmcnt for global_load_lds

        #pragma unroll
        for (int ks = 0; ks < 64; ks += 32) {
            bf16x8 aF[4], bF[4];
            const int cbase = (ks >> 3) + kc;   // 16B chunk col in [0,8)
            #pragma unroll
            for (int mi = 0; mi < 4; ++mi) {
                int r = wm + mi * 16 + mrow;
                int slot = r * 8 + (cbase ^ (r & 7));
                aF[mi] = *reinterpret_cast<const bf16x8*>(As + (size_t)slot * 8);
            }
            #pragma unroll
            for (int ni = 0; ni < 4; ++ni) {
                int r = wn + ni * 16 + mrow;
                int slot = r * 8 + (cbase ^ (r & 7));
                bF[ni] = *reinterpret_cast<const bf16x8*>(Bs + (size_t)slot * 8);
            }
            #pragma unroll
            for (int mi = 0; mi < 4; ++mi)
                #pragma unroll
                for (int ni = 0; ni < 4; ++ni)
                    acc[mi][ni] = __builtin_amdgcn_mfma_f32_16x16x32_bf16(
                        aF[mi], bF[ni], acc[mi][ni], 0, 0, 0);
        }
        __syncthreads();
    }

    // C/D layout (m89-verified): col = lane&15, row = (lane>>4)*4 + r
    const int orow = blockIdx.x * 128 + wm + (lane >> 4) * 4;
    const int ocol = blockIdx.y * 128 + wn + (lane & 15);
    #pragma unroll
    for (int mi = 0; mi < 4; ++mi)
        #pragma unroll
        for (int ni = 0; ni < 4; ++ni)
            #pragma unroll
            for (int r = 0; r < 4; ++r)
                unsafeAtomicAdd(
                    &C[(size_t)(orow + mi * 16 + r) * N + ocol + ni * 16],
                    acc[mi][ni][r]);
}

extern "C" void kernel_launch(void* const* d_in, const int* in_sizes, int n_in,
                              void* d_out, int out_size, void* d_ws, size_t ws_size,
                              hipStream_t stream)
{
    const float* x    = (const float*)d_in[0];   // [4096][512]
    const float* coef = (const float*)d_in[1];   // [512][512][8]
    float* out = (float*)d_out;                  // [4096][512]

    // workspace: jac bf16 [4096][4096] (32 MB) + coef bf16 [512][4096] (4 MB)
    unsigned short* jac   = (unsigned short*)d_ws;
    unsigned short* coefb = jac + (size_t)BATCH * KDIM;

    // split-K accumulates into d_out with atomics -> zero it first
    hipMemsetAsync(out, 0, (size_t)BATCH * OSZ * sizeof(float), stream);

    int nx = BATCH * ISZ;                        // 2,097,152
    jacobi_precompute<<<(nx + 255) / 256, 256, 0, stream>>>(x, jac, nx);

    int n4 = (OSZ * KDIM) / 4;                   // 524,288
    convert_bf16<<<(n4 + 255) / 256, 256, 0, stream>>>(coef, coefb, n4);

    dim3 grid(BATCH / 128, OSZ / 128, SPLITK);   // 32 x 4 x 4 = 512 blocks
    gemm_splitk<<<grid, 256, 0, stream>>>(jac, coefb, out, BATCH, OSZ, KDIM);
}